// Round 1
// baseline (226.170 us; speedup 1.0000x reference)
//
#include <hip/hip_runtime.h>
#include <hip/hip_bf16.h>
#include <math.h>

typedef short short8 __attribute__((ext_vector_type(8)));
typedef float f32x4 __attribute__((ext_vector_type(4)));

#define NN 8192
#define FIN 256
#define FOUT 128
#define LRELU_A 0.2f
#define L2E 1.44269504088896f

__device__ __forceinline__ short f2bf(float x) {
    unsigned u = __builtin_bit_cast(unsigned, x);
    unsigned r = (u + 0x7FFFu + ((u >> 16) & 1u)) >> 16;   // RNE
    return (short)r;
}

// K1: Wh = h @ W (fp32), fused f1 = Wh@a1, f2 = Wh@a2.
// Block = 256 threads, 8 rows/block. Thread = (row = tid>>5, cols = (tid&31)*4 .. +3).
__global__ __launch_bounds__(256) void k_wh(const float* __restrict__ h,
                                            const float* __restrict__ W,
                                            const float* __restrict__ a,
                                            float* __restrict__ Wh,
                                            float* __restrict__ f1,
                                            float* __restrict__ f2) {
    __shared__ float hs[8][FIN];
    const int tid = threadIdx.x;
    const int r0 = blockIdx.x * 8;
    #pragma unroll
    for (int i = 0; i < 2; ++i) {
        int f4 = tid + 256 * i;              // 512 float4 total
        int row = f4 >> 6;
        int k4 = (f4 & 63) << 2;
        *(float4*)&hs[row][k4] = *(const float4*)(h + (size_t)(r0 + row) * FIN + k4);
    }
    __syncthreads();
    const int c4 = (tid & 31) * 4;
    const int row = tid >> 5;
    float acc0 = 0.f, acc1 = 0.f, acc2 = 0.f, acc3 = 0.f;
    #pragma unroll 4
    for (int k = 0; k < FIN; ++k) {
        float hv = hs[row][k];
        float4 w4 = *(const float4*)(W + (size_t)k * FOUT + c4);
        acc0 = fmaf(hv, w4.x, acc0);
        acc1 = fmaf(hv, w4.y, acc1);
        acc2 = fmaf(hv, w4.z, acc2);
        acc3 = fmaf(hv, w4.w, acc3);
    }
    float4 o; o.x = acc0; o.y = acc1; o.z = acc2; o.w = acc3;
    *(float4*)(Wh + (size_t)(r0 + row) * FOUT + c4) = o;

    float4 a1v = *(const float4*)(a + c4);
    float4 a2v = *(const float4*)(a + FOUT + c4);
    float p1 = acc0 * a1v.x + acc1 * a1v.y + acc2 * a1v.z + acc3 * a1v.w;
    float p2 = acc0 * a2v.x + acc1 * a2v.y + acc2 * a2v.z + acc3 * a2v.w;
    #pragma unroll
    for (int m = 1; m <= 16; m <<= 1) {       // reduce across the 32 threads of one row
        p1 += __shfl_xor(p1, m, 64);
        p2 += __shfl_xor(p2, m, 64);
    }
    if ((tid & 31) == 0) {
        f1[r0 + row] = p1;
        f2[r0 + row] = p2;
    }
}

// K1t: WhT[c][r] = bf16(Wh[r][c]) via 32x32 LDS tiles.
__global__ __launch_bounds__(256) void k_transpose(const float* __restrict__ Wh,
                                                   short* __restrict__ WhT) {
    __shared__ float t32[32][33];
    const int tid = threadIdx.x;
    const int tx = tid & 31, ty = tid >> 5;     // ty in 0..7
    const int rb = (blockIdx.x & 255) * 32;
    const int cb = (blockIdx.x >> 8) * 32;
    #pragma unroll
    for (int q = 0; q < 4; ++q) {
        int r = ty + q * 8;
        t32[r][tx] = Wh[(size_t)(rb + r) * FOUT + cb + tx];
    }
    __syncthreads();
    #pragma unroll
    for (int q = 0; q < 4; ++q) {
        int c = ty + q * 8;
        WhT[(size_t)(cb + c) * NN + rb + tx] = f2bf(t32[tx][c]);
    }
}

// K1c: gmax = max(f2)
__global__ __launch_bounds__(256) void k_gmax(const float* __restrict__ f2,
                                              float* __restrict__ gmax) {
    const int tid = threadIdx.x;
    float m = -1e30f;
    for (int i = tid; i < NN; i += 256) m = fmaxf(m, f2[i]);
    #pragma unroll
    for (int s = 1; s <= 32; s <<= 1) m = fmaxf(m, __shfl_xor(m, s, 64));
    __shared__ float red[4];
    if ((tid & 63) == 0) red[tid >> 6] = m;
    __syncthreads();
    if (tid == 0) gmax[0] = fmaxf(fmaxf(red[0], red[1]), fmaxf(red[2], red[3]));
}

// K2: fused mask + leaky_relu + exp + (P @ Wh) via mfma_f32_16x16x32_bf16.
// Block = 4 waves, 64 rows; wave = 16 rows; split-K over j.
// A-frag: row = lane&15, k = (lane>>4)*8 + i. B-frag: col = lane&15, same k.
// D: col = lane&15, row = (lane>>4)*4 + reg.
__global__ __launch_bounds__(256) void k_attn(const int* __restrict__ adj,
                                              const short* __restrict__ WhT,
                                              const float* __restrict__ f1,
                                              const float* __restrict__ f2,
                                              const float* __restrict__ gmax,
                                              float* __restrict__ numb,
                                              float* __restrict__ denb,
                                              int kchunk) {
    const int tid = threadIdx.x;
    const int lane = tid & 63;
    const int wave = tid >> 6;
    const int nrt = NN / 64;                 // 128 row tiles
    const int rt = blockIdx.x % nrt;
    const int split = blockIdx.x / nrt;
    const int rowbase = rt * 64 + wave * 16;
    const int arow = rowbase + (lane & 15);
    const int kg = lane >> 4;

    const float f1r = f1[arow];
    const float gm = gmax[0];
    const float t0 = f1r + gm;
    const float mhat = fmaxf(t0, LRELU_A * t0);     // row max upper bound
    const float mh2 = mhat * L2E;

    const int kbase = split * kchunk + kg * 8;
    const int* adjrow = adj + (size_t)arow * NN + kbase;
    const float* f2p = f2 + kbase;
    const short* wb = WhT + kbase;

    f32x4 acc[8] = {};
    float den = 0.0f;
    const int niter = kchunk / 32;

    for (int it = 0; it < niter; ++it) {
        const int koff = it * 32;
        int4 av0 = *(const int4*)(adjrow + koff);
        int4 av1 = *(const int4*)(adjrow + koff + 4);
        float4 fa = *(const float4*)(f2p + koff);
        float4 fb = *(const float4*)(f2p + koff + 4);

        float fv[8] = {fa.x, fa.y, fa.z, fa.w, fb.x, fb.y, fb.z, fb.w};
        int mk[8] = {av0.x, av0.y, av0.z, av0.w, av1.x, av1.y, av1.z, av1.w};
        short8 af;
        #pragma unroll
        for (int i = 0; i < 8; ++i) {
            float e = f1r + fv[i];
            e = fmaxf(e, LRELU_A * e);                       // leaky_relu
            float p = __builtin_amdgcn_exp2f(fmaf(e, L2E, -mh2));
            p = mk[i] ? p : 0.0f;                            // adjacency mask
            den += p;
            af[i] = f2bf(p);
        }
        #pragma unroll
        for (int t = 0; t < 8; ++t) {
            short8 bv = *(const short8*)(wb + (size_t)(t * 16 + (lane & 15)) * NN + koff);
            acc[t] = __builtin_amdgcn_mfma_f32_16x16x32_bf16(af, bv, acc[t], 0, 0, 0);
        }
    }

    // full row-sum of p for this split's k range (reduce across the 4 k-groups)
    den += __shfl_xor(den, 16, 64);
    den += __shfl_xor(den, 32, 64);
    if (lane < 16) denb[(size_t)split * NN + rowbase + lane] = den;

    float* np = numb + ((size_t)split * NN + rowbase) * FOUT;
    const int col = lane & 15;
    const int rsub = (lane >> 4) * 4;
    #pragma unroll
    for (int t = 0; t < 8; ++t) {
        #pragma unroll
        for (int r = 0; r < 4; ++r) {
            np[(size_t)(rsub + r) * FOUT + t * 16 + col] = acc[t][r];
        }
    }
}

// K3: sum split partials, divide, ELU.
__global__ __launch_bounds__(256) void k_final(const float* __restrict__ numb,
                                               const float* __restrict__ denb,
                                               float* __restrict__ out,
                                               int splitk) {
    const int idx = blockIdx.x * 256 + threadIdx.x;
    const int row = idx >> 7;
    float s = 0.0f, d = 0.0f;
    for (int sp = 0; sp < splitk; ++sp) {
        s += numb[((size_t)sp * NN) * FOUT + idx];
        d += denb[(size_t)sp * NN + row];
    }
    float v = s / d;
    out[idx] = v > 0.0f ? v : expm1f(v);
}

extern "C" void kernel_launch(void* const* d_in, const int* in_sizes, int n_in,
                              void* d_out, int out_size, void* d_ws, size_t ws_size,
                              hipStream_t stream) {
    const float* h = (const float*)d_in[0];
    const int* adj = (const int*)d_in[1];
    const float* W = (const float*)d_in[2];
    const float* a = (const float*)d_in[3];
    float* out = (float*)d_out;

    char* ws = (char*)d_ws;
    size_t off = 0;
    auto alloc = [&](size_t nbytes) {
        char* p = ws + off;
        off = (off + nbytes + 255) & ~(size_t)255;
        return p;
    };
    float* Wh  = (float*)alloc((size_t)NN * FOUT * 4);
    short* WhT = (short*)alloc((size_t)FOUT * NN * 2);
    float* f1  = (float*)alloc(NN * 4);
    float* f2  = (float*)alloc(NN * 4);
    float* gmx = (float*)alloc(256);

    int splitk = 8;
    while (splitk > 1 &&
           off + (size_t)splitk * ((size_t)NN * FOUT * 4 + NN * 4 + 512) > ws_size)
        splitk >>= 1;
    float* numb = (float*)alloc((size_t)splitk * NN * FOUT * 4);
    float* denb = (float*)alloc((size_t)splitk * NN * 4);
    const int kchunk = NN / splitk;

    k_wh<<<NN / 8, 256, 0, stream>>>(h, W, a, Wh, f1, f2);
    k_transpose<<<(NN / 32) * (FOUT / 32), 256, 0, stream>>>(Wh, WhT);
    k_gmax<<<1, 256, 0, stream>>>(f2, gmx);
    k_attn<<<(NN / 64) * splitk, 256, 0, stream>>>(adj, WhT, f1, f2, gmx, numb, denb, kchunk);
    k_final<<<NN * FOUT / 256, 256, 0, stream>>>(numb, denb, out, splitk);
}

// Round 2
// 219.640 us; speedup vs baseline: 1.0297x; 1.0297x over previous
//
#include <hip/hip_runtime.h>
#include <hip/hip_bf16.h>
#include <math.h>

typedef short short8 __attribute__((ext_vector_type(8)));
typedef float f32x4 __attribute__((ext_vector_type(4)));

#define NN 8192
#define FIN 256
#define FOUT 128
#define LRELU_A 0.2f
#define L2E 1.44269504088896f

__device__ __forceinline__ short f2bf(float x) {
    unsigned u = __builtin_bit_cast(unsigned, x);
    unsigned r = (u + 0x7FFFu + ((u >> 16) & 1u)) >> 16;   // RNE
    return (short)r;
}

// K1: Wh = h @ W (fp32), fused f1 = Wh@a1, f2 = Wh@a2.
__global__ __launch_bounds__(256) void k_wh(const float* __restrict__ h,
                                            const float* __restrict__ W,
                                            const float* __restrict__ a,
                                            float* __restrict__ Wh,
                                            float* __restrict__ f1,
                                            float* __restrict__ f2) {
    __shared__ float hs[8][FIN];
    const int tid = threadIdx.x;
    const int r0 = blockIdx.x * 8;
    #pragma unroll
    for (int i = 0; i < 2; ++i) {
        int f4 = tid + 256 * i;              // 512 float4 total
        int row = f4 >> 6;
        int k4 = (f4 & 63) << 2;
        *(float4*)&hs[row][k4] = *(const float4*)(h + (size_t)(r0 + row) * FIN + k4);
    }
    __syncthreads();
    const int c4 = (tid & 31) * 4;
    const int row = tid >> 5;
    float acc0 = 0.f, acc1 = 0.f, acc2 = 0.f, acc3 = 0.f;
    #pragma unroll 4
    for (int k = 0; k < FIN; ++k) {
        float hv = hs[row][k];
        float4 w4 = *(const float4*)(W + (size_t)k * FOUT + c4);
        acc0 = fmaf(hv, w4.x, acc0);
        acc1 = fmaf(hv, w4.y, acc1);
        acc2 = fmaf(hv, w4.z, acc2);
        acc3 = fmaf(hv, w4.w, acc3);
    }
    float4 o; o.x = acc0; o.y = acc1; o.z = acc2; o.w = acc3;
    *(float4*)(Wh + (size_t)(r0 + row) * FOUT + c4) = o;

    float4 a1v = *(const float4*)(a + c4);
    float4 a2v = *(const float4*)(a + FOUT + c4);
    float p1 = acc0 * a1v.x + acc1 * a1v.y + acc2 * a1v.z + acc3 * a1v.w;
    float p2 = acc0 * a2v.x + acc1 * a2v.y + acc2 * a2v.z + acc3 * a2v.w;
    #pragma unroll
    for (int m = 1; m <= 16; m <<= 1) {
        p1 += __shfl_xor(p1, m, 64);
        p2 += __shfl_xor(p2, m, 64);
    }
    if ((tid & 31) == 0) {
        f1[r0 + row] = p1;
        f2[r0 + row] = p2;
    }
}

// K1t: WhT[c][r] = bf16(Wh[r][c]) via 32x32 LDS tiles.
__global__ __launch_bounds__(256) void k_transpose(const float* __restrict__ Wh,
                                                   short* __restrict__ WhT) {
    __shared__ float t32[32][33];
    const int tid = threadIdx.x;
    const int tx = tid & 31, ty = tid >> 5;
    const int rb = (blockIdx.x & 255) * 32;
    const int cb = (blockIdx.x >> 8) * 32;
    #pragma unroll
    for (int q = 0; q < 4; ++q) {
        int r = ty + q * 8;
        t32[r][tx] = Wh[(size_t)(rb + r) * FOUT + cb + tx];
    }
    __syncthreads();
    #pragma unroll
    for (int q = 0; q < 4; ++q) {
        int c = ty + q * 8;
        WhT[(size_t)(cb + c) * NN + rb + tx] = f2bf(t32[tx][c]);
    }
}

// K1c: gmax = max(f2)
__global__ __launch_bounds__(256) void k_gmax(const float* __restrict__ f2,
                                              float* __restrict__ gmax) {
    const int tid = threadIdx.x;
    float m = -1e30f;
    for (int i = tid; i < NN; i += 256) m = fmaxf(m, f2[i]);
    #pragma unroll
    for (int s = 1; s <= 32; s <<= 1) m = fmaxf(m, __shfl_xor(m, s, 64));
    __shared__ float red[4];
    if ((tid & 63) == 0) red[tid >> 6] = m;
    __syncthreads();
    if (tid == 0) gmax[0] = fmaxf(fmaxf(red[0], red[1]), fmaxf(red[2], red[3]));
}

// K2: fused mask + leaky_relu + exp + (P @ Wh) via mfma_f32_16x16x32_bf16.
// Barrier-free, register software-pipelined (unroll-2, named reg sets).
// split = bid & 7  -> all blocks on one XCD share a WhT/f2 slice in its L2.
__global__ __launch_bounds__(256, 4) void k_attn(const int* __restrict__ adj,
                                                 const short* __restrict__ WhT,
                                                 const float* __restrict__ f1,
                                                 const float* __restrict__ f2,
                                                 const float* __restrict__ gmax,
                                                 float* __restrict__ numb,
                                                 float* __restrict__ denb,
                                                 int kchunk, int nsplit) {
    const int tid = threadIdx.x;
    const int lane = tid & 63;
    const int wave = tid >> 6;
    const int split = blockIdx.x & (nsplit - 1);
    const int rt = blockIdx.x / nsplit;
    const int rowbase = rt * 64 + wave * 16;
    const int arow = rowbase + (lane & 15);
    const int kg = lane >> 4;

    const float f1r = f1[arow];
    const float gm = gmax[0];
    const float t0 = f1r + gm;
    const float mhat = fmaxf(t0, LRELU_A * t0);     // row max upper bound
    const float mh2 = mhat * L2E;

    const int kbase = split * kchunk + kg * 8;
    const int* adjrow = adj + (size_t)arow * NN + kbase;
    const float* f2p = f2 + kbase;
    const short* wb = WhT + (size_t)(lane & 15) * NN + kbase;

    f32x4 acc[8] = {};
    float den = 0.0f;

    // prologue: A-set holds data for koff = 0
    int4 a0A = *(const int4*)(adjrow);
    int4 a1A = *(const int4*)(adjrow + 4);
    float4 faA = *(const float4*)(f2p);
    float4 fbA = *(const float4*)(f2p + 4);

    for (int koff = 0; koff < kchunk; koff += 64) {
        // ---- prefetch B-set (adj/f2 for koff+32), issue early ----
        int4 a0B = *(const int4*)(adjrow + koff + 32);
        int4 a1B = *(const int4*)(adjrow + koff + 36);
        float4 faB = *(const float4*)(f2p + koff + 32);
        float4 fbB = *(const float4*)(f2p + koff + 36);

        // ---- body A: koff ----
        {
            short8 b0 = *(const short8*)(wb + (size_t)(0 * 16) * NN + koff);
            short8 b1 = *(const short8*)(wb + (size_t)(1 * 16) * NN + koff);
            short8 b2 = *(const short8*)(wb + (size_t)(2 * 16) * NN + koff);
            short8 b3 = *(const short8*)(wb + (size_t)(3 * 16) * NN + koff);
            short8 b4 = *(const short8*)(wb + (size_t)(4 * 16) * NN + koff);
            short8 b5 = *(const short8*)(wb + (size_t)(5 * 16) * NN + koff);
            short8 b6 = *(const short8*)(wb + (size_t)(6 * 16) * NN + koff);
            short8 b7 = *(const short8*)(wb + (size_t)(7 * 16) * NN + koff);

            float fv[8] = {faA.x, faA.y, faA.z, faA.w, fbA.x, fbA.y, fbA.z, fbA.w};
            int mk[8] = {a0A.x, a0A.y, a0A.z, a0A.w, a1A.x, a1A.y, a1A.z, a1A.w};
            short8 af;
            #pragma unroll
            for (int i = 0; i < 8; ++i) {
                float e = f1r + fv[i];
                e = fmaxf(e, LRELU_A * e);
                float p = __builtin_amdgcn_exp2f(fmaf(e, L2E, -mh2));
                p = mk[i] ? p : 0.0f;
                den += p;
                af[i] = f2bf(p);
            }

            // ---- prefetch A-set for koff+64 (guarded, uniform select) ----
            {
                const int kn = (koff + 64 < kchunk) ? koff + 64 : 0;
                a0A = *(const int4*)(adjrow + kn);
                a1A = *(const int4*)(adjrow + kn + 4);
                faA = *(const float4*)(f2p + kn);
                fbA = *(const float4*)(f2p + kn + 4);
            }

            acc[0] = __builtin_amdgcn_mfma_f32_16x16x32_bf16(af, b0, acc[0], 0, 0, 0);
            acc[1] = __builtin_amdgcn_mfma_f32_16x16x32_bf16(af, b1, acc[1], 0, 0, 0);
            acc[2] = __builtin_amdgcn_mfma_f32_16x16x32_bf16(af, b2, acc[2], 0, 0, 0);
            acc[3] = __builtin_amdgcn_mfma_f32_16x16x32_bf16(af, b3, acc[3], 0, 0, 0);
            acc[4] = __builtin_amdgcn_mfma_f32_16x16x32_bf16(af, b4, acc[4], 0, 0, 0);
            acc[5] = __builtin_amdgcn_mfma_f32_16x16x32_bf16(af, b5, acc[5], 0, 0, 0);
            acc[6] = __builtin_amdgcn_mfma_f32_16x16x32_bf16(af, b6, acc[6], 0, 0, 0);
            acc[7] = __builtin_amdgcn_mfma_f32_16x16x32_bf16(af, b7, acc[7], 0, 0, 0);
        }

        // ---- body B: koff+32 ----
        {
            const int kb = koff + 32;
            short8 b0 = *(const short8*)(wb + (size_t)(0 * 16) * NN + kb);
            short8 b1 = *(const short8*)(wb + (size_t)(1 * 16) * NN + kb);
            short8 b2 = *(const short8*)(wb + (size_t)(2 * 16) * NN + kb);
            short8 b3 = *(const short8*)(wb + (size_t)(3 * 16) * NN + kb);
            short8 b4 = *(const short8*)(wb + (size_t)(4 * 16) * NN + kb);
            short8 b5 = *(const short8*)(wb + (size_t)(5 * 16) * NN + kb);
            short8 b6 = *(const short8*)(wb + (size_t)(6 * 16) * NN + kb);
            short8 b7 = *(const short8*)(wb + (size_t)(7 * 16) * NN + kb);

            float fv[8] = {faB.x, faB.y, faB.z, faB.w, fbB.x, fbB.y, fbB.z, fbB.w};
            int mk[8] = {a0B.x, a0B.y, a0B.z, a0B.w, a1B.x, a1B.y, a1B.z, a1B.w};
            short8 af;
            #pragma unroll
            for (int i = 0; i < 8; ++i) {
                float e = f1r + fv[i];
                e = fmaxf(e, LRELU_A * e);
                float p = __builtin_amdgcn_exp2f(fmaf(e, L2E, -mh2));
                p = mk[i] ? p : 0.0f;
                den += p;
                af[i] = f2bf(p);
            }

            acc[0] = __builtin_amdgcn_mfma_f32_16x16x32_bf16(af, b0, acc[0], 0, 0, 0);
            acc[1] = __builtin_amdgcn_mfma_f32_16x16x32_bf16(af, b1, acc[1], 0, 0, 0);
            acc[2] = __builtin_amdgcn_mfma_f32_16x16x32_bf16(af, b2, acc[2], 0, 0, 0);
            acc[3] = __builtin_amdgcn_mfma_f32_16x16x32_bf16(af, b3, acc[3], 0, 0, 0);
            acc[4] = __builtin_amdgcn_mfma_f32_16x16x32_bf16(af, b4, acc[4], 0, 0, 0);
            acc[5] = __builtin_amdgcn_mfma_f32_16x16x32_bf16(af, b5, acc[5], 0, 0, 0);
            acc[6] = __builtin_amdgcn_mfma_f32_16x16x32_bf16(af, b6, acc[6], 0, 0, 0);
            acc[7] = __builtin_amdgcn_mfma_f32_16x16x32_bf16(af, b7, acc[7], 0, 0, 0);
        }
    }

    // reduce den across the 4 k-groups
    den += __shfl_xor(den, 16, 64);
    den += __shfl_xor(den, 32, 64);
    if (lane < 16) denb[(size_t)split * NN + rowbase + lane] = den;

    float* np = numb + ((size_t)split * NN + rowbase) * FOUT;
    const int col = lane & 15;
    const int rsub = (lane >> 4) * 4;
    #pragma unroll
    for (int t = 0; t < 8; ++t) {
        #pragma unroll
        for (int r = 0; r < 4; ++r) {
            np[(size_t)(rsub + r) * FOUT + t * 16 + col] = acc[t][r];
        }
    }
}

// K3: sum split partials, divide, ELU.
__global__ __launch_bounds__(256) void k_final(const float* __restrict__ numb,
                                               const float* __restrict__ denb,
                                               float* __restrict__ out,
                                               int splitk) {
    const int idx = blockIdx.x * 256 + threadIdx.x;
    const int row = idx >> 7;
    float s = 0.0f, d = 0.0f;
    for (int sp = 0; sp < splitk; ++sp) {
        s += numb[((size_t)sp * NN) * FOUT + idx];
        d += denb[(size_t)sp * NN + row];
    }
    float v = s / d;
    out[idx] = v > 0.0f ? v : expm1f(v);
}

extern "C" void kernel_launch(void* const* d_in, const int* in_sizes, int n_in,
                              void* d_out, int out_size, void* d_ws, size_t ws_size,
                              hipStream_t stream) {
    const float* h = (const float*)d_in[0];
    const int* adj = (const int*)d_in[1];
    const float* W = (const float*)d_in[2];
    const float* a = (const float*)d_in[3];
    float* out = (float*)d_out;

    char* ws = (char*)d_ws;
    size_t off = 0;
    auto alloc = [&](size_t nbytes) {
        char* p = ws + off;
        off = (off + nbytes + 255) & ~(size_t)255;
        return p;
    };
    float* Wh  = (float*)alloc((size_t)NN * FOUT * 4);
    short* WhT = (short*)alloc((size_t)FOUT * NN * 2);
    float* f1  = (float*)alloc(NN * 4);
    float* f2  = (float*)alloc(NN * 4);
    float* gmx = (float*)alloc(256);

    int splitk = 8;
    while (splitk > 1 &&
           off + (size_t)splitk * ((size_t)NN * FOUT * 4 + NN * 4 + 512) > ws_size)
        splitk >>= 1;
    float* numb = (float*)alloc((size_t)splitk * NN * FOUT * 4);
    float* denb = (float*)alloc((size_t)splitk * NN * 4);
    const int kchunk = NN / splitk;

    k_wh<<<NN / 8, 256, 0, stream>>>(h, W, a, Wh, f1, f2);
    k_transpose<<<(NN / 32) * (FOUT / 32), 256, 0, stream>>>(Wh, WhT);
    k_gmax<<<1, 256, 0, stream>>>(f2, gmx);
    k_attn<<<(NN / 64) * splitk, 256, 0, stream>>>(adj, WhT, f1, f2, gmx, numb, denb,
                                                   kchunk, splitk);
    k_final<<<NN * FOUT / 256, 256, 0, stream>>>(numb, denb, out, splitk);
}